// Round 2
// baseline (2716.499 us; speedup 1.0000x reference)
//
#include <hip/hip_runtime.h>
#include <hip/hip_bf16.h>
#include <math.h>

#define NPOS 131072   // N
#define NF   69       // FEAT
#define NMRG 32768    // N/4
#define TILE 2048
#define TPS  64       // NPOS/TILE
#define NSORT 4

// ---------------- stable argsort: LSD radix, 4x8-bit ----------------
__global__ void k_make_keys(const float* __restrict__ inp, unsigned* __restrict__ kA,
                            unsigned* __restrict__ vA){
  unsigned t = blockIdx.x*256u + threadIdx.x;       // t < 4*NPOS
  unsigned s = t >> 17, i = t & (NPOS-1u);
  unsigned b = s >> 1, ch = 3u + (s & 1u);          // s=b*2+c; c=0 -> ch3, c=1 -> ch4
  float x = inp[((size_t)b*NPOS + i)*NF + ch];
  unsigned u = __float_as_uint(x);
  u = (u & 0x80000000u) ? ~u : (u | 0x80000000u);   // ascending-float order as uint
  kA[t] = u; vA[t] = i;
}

__global__ __launch_bounds__(256) void k_hist(const unsigned* __restrict__ src,
                                              unsigned* __restrict__ hist, int shift){
  __shared__ unsigned h[256];
  int tid = threadIdx.x;
  h[tid] = 0u; __syncthreads();
  int s = blockIdx.x / TPS, tile = blockIdx.x % TPS;
  const unsigned* ks = src + (size_t)s*NPOS + (size_t)tile*TILE;
  for (int r = 0; r < TILE/256; ++r){
    unsigned d = (ks[r*256 + tid] >> shift) & 255u;
    atomicAdd(&h[d], 1u);
  }
  __syncthreads();
  hist[s*16384 + tid*TPS + tile] = h[tid];          // [s][bin][tile]
}

__global__ __launch_bounds__(256) void k_scan(unsigned* __restrict__ hist){
  __shared__ unsigned tot[256];
  int tid = threadIdx.x; int s = blockIdx.x;
  unsigned* g = hist + s*16384;
  unsigned sum = 0;
  for (int q = 0; q < 64; ++q) sum += g[tid*64 + q];
  tot[tid] = sum;
  __syncthreads();
  if (tid == 0){
    unsigned run = 0;
    for (int t = 0; t < 256; ++t){ unsigned tmp = tot[t]; tot[t] = run; run += tmp; }
  }
  __syncthreads();
  unsigned run = tot[tid];
  for (int q = 0; q < 64; ++q){ unsigned tmp = g[tid*64+q]; g[tid*64+q] = run; run += tmp; }
}

#define EPT 16
__global__ __launch_bounds__(128) void k_scatter(const unsigned* __restrict__ srcK,
    const unsigned* __restrict__ srcV, unsigned* __restrict__ dstK, unsigned* __restrict__ dstV,
    const unsigned* __restrict__ off, int shift){
  __shared__ unsigned short cnt[256*128];           // [digit][thread], 64KB
  int tid = threadIdx.x;
  unsigned* cz = (unsigned*)cnt;
  for (int idx = tid; idx < 256*128/2; idx += 128) cz[idx] = 0u;
  __syncthreads();
  int s = blockIdx.x / TPS, tile = blockIdx.x % TPS;
  const unsigned* ks = srcK + (size_t)s*NPOS + (size_t)tile*TILE;
  const unsigned* vs = srcV + (size_t)s*NPOS + (size_t)tile*TILE;
  unsigned k8[EPT], v8[EPT];
  #pragma unroll
  for (int r = 0; r < EPT; ++r){                    // thread t owns elems [t*16, t*16+16)
    k8[r] = ks[tid*EPT + r];
    v8[r] = vs[tid*EPT + r];
    unsigned d = (k8[r] >> shift) & 255u;
    cnt[d*128 + tid]++;
  }
  __syncthreads();
  for (int dd = 0; dd < 2; ++dd){                   // exclusive scan over threads per digit
    int d = tid + dd*128;
    unsigned run = 0;
    for (int t = 0; t < 128; ++t){ unsigned tmp = cnt[d*128 + t]; cnt[d*128 + t] = (unsigned short)run; run += tmp; }
  }
  __syncthreads();
  const unsigned* ob = off + s*16384;
  #pragma unroll
  for (int r = 0; r < EPT; ++r){                    // stable scatter
    unsigned d = (k8[r] >> shift) & 255u;
    unsigned rk = cnt[d*128 + tid];
    cnt[d*128 + tid] = (unsigned short)(rk + 1u);
    unsigned pos = ob[d*TPS + tile] + rk;
    dstK[(size_t)s*NPOS + pos] = k8[r];
    dstV[(size_t)s*NPOS + pos] = v8[r];
  }
}

// ---------------- gather sorted rows ----------------
__global__ void k_gather(const float* __restrict__ inp, const unsigned* __restrict__ P,
                         float* __restrict__ X0, int b){
  int t = blockIdx.x*256 + threadIdx.x;
  if (t >= NPOS*NF) return;
  int i = t / NF, c = t - i*NF;
  X0[t] = inp[((size_t)b*NPOS + P[i])*NF + c];
}

// ---------------- width-3 SAME conv + relu, 2 src concat ----------------
template<int CIN>
__global__ __launch_bounds__(128) void k_conv3(const float* __restrict__ Xa,
    const float* __restrict__ Xb, int ca, const float* __restrict__ W,
    const float* __restrict__ bias, float* __restrict__ out, int n){
  __shared__ float xl[CIN][36];                     // [channel][row], 16B-aligned rows
  int tid = threadIdx.x;
  int i0 = blockIdx.x * 32;
  for (int idx = tid; idx < 34*CIN; idx += 128){
    int r = idx / CIN, c = idx - r*CIN;
    int row = i0 - 1 + r;
    float v = 0.f;
    if (row >= 0 && row < n)
      v = (c < ca) ? Xa[(size_t)row*ca + c] : Xb[(size_t)row*(CIN-ca) + (c - ca)];
    xl[c][r] = v;
  }
  __syncthreads();
  int o2 = tid & 63, h = tid >> 6;                  // 2 out-ch x 16 positions per thread
  float acc0[16], acc1[16];
  #pragma unroll
  for (int p = 0; p < 16; ++p){ acc0[p] = 0.f; acc1[p] = 0.f; }
  for (int c = 0; c < CIN; ++c){
    float xv[18];
    #pragma unroll
    for (int q = 0; q < 18; ++q) xv[q] = xl[c][h*16 + q];
    #pragma unroll
    for (int k = 0; k < 3; ++k){
      float w0 = W[(k*CIN + c)*128 + o2];
      float w1 = W[(k*CIN + c)*128 + o2 + 64];
      #pragma unroll
      for (int p = 0; p < 16; ++p){
        acc0[p] = fmaf(xv[p+k], w0, acc0[p]);
        acc1[p] = fmaf(xv[p+k], w1, acc1[p]);
      }
    }
  }
  float b0 = bias[o2], b1 = bias[o2 + 64];
  #pragma unroll
  for (int p = 0; p < 16; ++p){
    size_t i = (size_t)(i0 + h*16 + p);
    out[i*128 + o2]      = fmaxf(acc0[p] + b0, 0.f);
    out[i*128 + o2 + 64] = fmaxf(acc1[p] + b1, 0.f);
  }
}

// ---------------- flags head: sigmoid(X3 @ Wf + bf) ----------------
__global__ __launch_bounds__(256) void k_flags(const float* __restrict__ X0,
    const float* __restrict__ Bc, const float* __restrict__ inp, const unsigned* __restrict__ P0,
    const float* __restrict__ Wf, const float* __restrict__ bf, float* __restrict__ F, int b){
  size_t i = (size_t)blockIdx.x*256 + threadIdx.x;
  float a0 = bf[0], a1 = bf[1], a2 = bf[2], a3 = bf[3];
  const float* x0 = X0 + i*NF;
  for (int c = 0; c < NF; ++c){
    float x = x0[c]; const float* w = Wf + c*4;
    a0 = fmaf(x,w[0],a0); a1 = fmaf(x,w[1],a1); a2 = fmaf(x,w[2],a2); a3 = fmaf(x,w[3],a3);
  }
  const float* bc = Bc + i*128;
  for (int c = 0; c < 128; ++c){
    float x = bc[c]; const float* w = Wf + (NF + c)*4;
    a0 = fmaf(x,w[0],a0); a1 = fmaf(x,w[1],a1); a2 = fmaf(x,w[2],a2); a3 = fmaf(x,w[3],a3);
  }
  const float* g = inp + ((size_t)b*NPOS + P0[i])*NF;
  for (int c = 0; c < NF; ++c){
    float x = g[c]; const float* w = Wf + (197 + c)*4;
    a0 = fmaf(x,w[0],a0); a1 = fmaf(x,w[1],a1); a2 = fmaf(x,w[2],a2); a3 = fmaf(x,w[3],a3);
  }
  float* f = F + i*4;
  f[0] = 1.f/(1.f+expf(-a0)); f[1] = 1.f/(1.f+expf(-a1));
  f[2] = 1.f/(1.f+expf(-a2)); f[3] = 1.f/(1.f+expf(-a3));
}

// ---------------- merge conv: width 4, stride 4, VALID, C=270 ----------------
__global__ __launch_bounds__(128) void k_merge(const float* __restrict__ F,
    const float* __restrict__ X0, const float* __restrict__ Bc, const float* __restrict__ inp,
    const unsigned* __restrict__ P0, const float* __restrict__ Wm, const float* __restrict__ bm,
    float* __restrict__ M, int b){
  __shared__ float xl[135][64];                     // half the channels at a time
  int tid = threadIdx.x;
  int j0 = blockIdx.x * 16;
  int r0 = 4*j0;
  int o2 = tid & 63, h = tid >> 6;
  float acc0[8], acc1[8];
  #pragma unroll
  for (int j = 0; j < 8; ++j){ acc0[j]=0.f; acc1[j]=0.f; }
  for (int half = 0; half < 2; ++half){
    int cb = half*135;
    __syncthreads();
    for (int idx = tid; idx < 135*64; idx += 128){
      int cc = idx >> 6, rr = idx & 63;
      int c = cb + cc, r = r0 + rr;
      float v;
      if (c < 4)        v = F[(size_t)r*4 + c];
      else if (c < 73)  v = X0[(size_t)r*NF + (c-4)];
      else if (c < 201) v = Bc[(size_t)r*128 + (c-73)];
      else              v = inp[((size_t)b*NPOS + P0[r])*NF + (c-201)];
      xl[cc][rr] = v;
    }
    __syncthreads();
    for (int cc = 0; cc < 135; ++cc){
      int c = cb + cc;
      float xv[32];
      #pragma unroll
      for (int q = 0; q < 32; ++q) xv[q] = xl[cc][h*32 + q];
      #pragma unroll
      for (int k = 0; k < 4; ++k){
        float w0 = Wm[(size_t)(k*270 + c)*128 + o2];
        float w1 = Wm[(size_t)(k*270 + c)*128 + o2 + 64];
        #pragma unroll
        for (int j = 0; j < 8; ++j){
          acc0[j] = fmaf(xv[4*j+k], w0, acc0[j]);
          acc1[j] = fmaf(xv[4*j+k], w1, acc1[j]);
        }
      }
    }
  }
  float bb0 = bm[o2], bb1 = bm[o2+64];
  #pragma unroll
  for (int j = 0; j < 8; ++j){
    size_t jj = (size_t)(j0 + h*8 + j);
    M[jj*128 + o2]      = fmaxf(acc0[j] + bb0, 0.f);
    M[jj*128 + o2 + 64] = fmaxf(acc1[j] + bb1, 0.f);
  }
}

// ---------------- output head: softmax(S@Ws+bs) + flag diff, f32 out ----------------
__global__ __launch_bounds__(256) void k_out(const float* __restrict__ S,
    const float* __restrict__ F, const float* __restrict__ Ws, const float* __restrict__ bs,
    float* __restrict__ out, int b){
  size_t j = (size_t)blockIdx.x*256 + threadIdx.x;
  float l[16];
  #pragma unroll
  for (int t = 0; t < 16; ++t) l[t] = bs[t];
  const float* s = S + j*128;
  for (int c = 0; c < 128; ++c){
    float x = s[c]; const float* w = Ws + c*16;
    #pragma unroll
    for (int t = 0; t < 16; ++t) l[t] = fmaf(x, w[t], l[t]);
  }
  float m = l[0];
  #pragma unroll
  for (int t = 1; t < 16; ++t) m = fmaxf(m, l[t]);
  float sum = 0.f;
  #pragma unroll
  for (int t = 0; t < 16; ++t){ l[t] = expf(l[t]-m); sum += l[t]; }
  float inv = 1.f/sum;
  float* o = out + ((size_t)b*NMRG + j)*20;
  #pragma unroll
  for (int k = 0; k < 4; ++k){
    size_t r = (size_t)(4*j + k)*4;
    o[k] = F[r] - F[r+1];
  }
  #pragma unroll
  for (int t = 0; t < 16; ++t) o[4+t] = l[t]*inv;
}

extern "C" void kernel_launch(void* const* d_in, const int* in_sizes, int n_in,
                              void* d_out, int out_size, void* d_ws, size_t ws_size,
                              hipStream_t stream){
  const float* inp     = (const float*)d_in[0];
  const float* w_pre0  = (const float*)d_in[1];
  const float* b_pre0  = (const float*)d_in[2];
  const float* w_pre1  = (const float*)d_in[3];
  const float* b_pre1  = (const float*)d_in[4];
  const float* w_flags = (const float*)d_in[5];
  const float* b_flags = (const float*)d_in[6];
  const float* w_merge = (const float*)d_in[7];
  const float* b_merge = (const float*)d_in[8];
  const float* w_post[4] = {(const float*)d_in[9], (const float*)d_in[11],
                            (const float*)d_in[13], (const float*)d_in[15]};
  const float* b_post[4] = {(const float*)d_in[10], (const float*)d_in[12],
                            (const float*)d_in[14], (const float*)d_in[16]};
  const float* w_sym   = (const float*)d_in[17];
  const float* b_sym   = (const float*)d_in[18];
  float* outp = (float*)d_out;

  char* p = (char*)d_ws;
  unsigned* kA = (unsigned*)p; p += (size_t)NSORT*NPOS*4;
  unsigned* vA = (unsigned*)p; p += (size_t)NSORT*NPOS*4;
  unsigned* kB = (unsigned*)p; p += (size_t)NSORT*NPOS*4;
  unsigned* vB = (unsigned*)p; p += (size_t)NSORT*NPOS*4;
  unsigned* hist = (unsigned*)p; p += (size_t)NSORT*16384*4;
  float* X0   = (float*)p; p += (size_t)NPOS*NF*4;
  float* Abuf = (float*)p; p += (size_t)NPOS*128*4;
  float* Bbuf = (float*)p; p += (size_t)NPOS*128*4;
  float* Fbuf = (float*)p; p += (size_t)NPOS*4*4;
  float* M0   = (float*)p; p += (size_t)NMRG*128*4;
  float* M1   = (float*)p; p += (size_t)NMRG*128*4;
  if ((size_t)(p - (char*)d_ws) > ws_size) return;  // ws too small: fail visibly

  k_make_keys<<<NSORT*NPOS/256, 256, 0, stream>>>(inp, kA, vA);
  unsigned *sk = kA, *sv = vA, *dk = kB, *dv = vB;
  for (int pass = 0; pass < 4; ++pass){
    int shift = pass*8;
    k_hist<<<NSORT*TPS, 256, 0, stream>>>(sk, hist, shift);
    k_scan<<<NSORT, 256, 0, stream>>>(hist);
    k_scatter<<<NSORT*TPS, 128, 0, stream>>>(sk, sv, dk, dv, hist, shift);
    unsigned* t;
    t = sk; sk = dk; dk = t;
    t = sv; sv = dv; dv = t;
  }
  // after 4 passes the sorted (key,val) pairs are back in kA/vA (== sk/sv)
  for (int b = 0; b < 2; ++b){
    const unsigned* P0 = sv + (size_t)(b*2+0)*NPOS;  // argsort of channel 3
    const unsigned* P1 = sv + (size_t)(b*2+1)*NPOS;  // argsort of channel 4
    k_gather<<<(NPOS*NF + 255)/256, 256, 0, stream>>>(inp, P1, X0, b);
    k_conv3<NF><<<NPOS/32, 128, 0, stream>>>(X0, X0, NF, w_pre0, b_pre0, Abuf, NPOS);
    k_conv3<197><<<NPOS/32, 128, 0, stream>>>(X0, Abuf, NF, w_pre1, b_pre1, Bbuf, NPOS);
    k_flags<<<NPOS/256, 256, 0, stream>>>(X0, Bbuf, inp, P0, w_flags, b_flags, Fbuf, b);
    k_merge<<<NMRG/16, 128, 0, stream>>>(Fbuf, X0, Bbuf, inp, P0, w_merge, b_merge, M0, b);
    k_conv3<128><<<NMRG/32, 128, 0, stream>>>(M0, M0, 128, w_post[0], b_post[0], M1, NMRG);
    k_conv3<128><<<NMRG/32, 128, 0, stream>>>(M1, M1, 128, w_post[1], b_post[1], M0, NMRG);
    k_conv3<128><<<NMRG/32, 128, 0, stream>>>(M0, M0, 128, w_post[2], b_post[2], M1, NMRG);
    k_conv3<128><<<NMRG/32, 128, 0, stream>>>(M1, M1, 128, w_post[3], b_post[3], M0, NMRG);
    k_out<<<NMRG/256, 256, 0, stream>>>(M0, Fbuf, w_sym, b_sym, outp, b);
  }
}

// Round 3
// 752.007 us; speedup vs baseline: 3.6123x; 3.6123x over previous
//
#include <hip/hip_runtime.h>
#include <hip/hip_bf16.h>
#include <math.h>

#define NPOS 131072   // N
#define NF   69       // FEAT
#define NMRG 32768    // N/4
#define TILE 2048
#define TPS  64       // NPOS/TILE
#define NSORT 4

typedef __attribute__((ext_vector_type(8))) short short8;
typedef __bf16 bf16x8 __attribute__((ext_vector_type(8)));
typedef __attribute__((ext_vector_type(4))) float f32x4;

static __device__ inline bf16x8 as_bf16x8(short8 v){ union{short8 s; bf16x8 b;} u; u.s=v; return u.b; }
static __device__ inline short f2bf(float x){ __hip_bfloat16 h = __float2bfloat16(x); return *(short*)&h; }
static __device__ inline float bf2f(short s){ return __uint_as_float(((unsigned)(unsigned short)s)<<16); }

// ---------------- stable argsort: LSD radix, 4x8-bit ----------------
__global__ void k_make_keys(const float* __restrict__ inp, unsigned* __restrict__ kA,
                            unsigned* __restrict__ vA){
  unsigned t = blockIdx.x*256u + threadIdx.x;
  unsigned s = t >> 17, i = t & (NPOS-1u);
  unsigned b = s >> 1, ch = 3u + (s & 1u);
  float x = inp[((size_t)b*NPOS + i)*NF + ch];
  unsigned u = __float_as_uint(x);
  u = (u & 0x80000000u) ? ~u : (u | 0x80000000u);
  kA[t] = u; vA[t] = i;
}

__global__ __launch_bounds__(256) void k_hist(const unsigned* __restrict__ src,
                                              unsigned* __restrict__ hist, int shift){
  __shared__ unsigned h[256];
  int tid = threadIdx.x;
  h[tid] = 0u; __syncthreads();
  int s = blockIdx.x / TPS, tile = blockIdx.x % TPS;
  const unsigned* ks = src + (size_t)s*NPOS + (size_t)tile*TILE;
  for (int r = 0; r < TILE/256; ++r){
    unsigned d = (ks[r*256 + tid] >> shift) & 255u;
    atomicAdd(&h[d], 1u);
  }
  __syncthreads();
  hist[s*16384 + tid*TPS + tile] = h[tid];
}

__global__ __launch_bounds__(256) void k_scan(unsigned* __restrict__ hist){
  __shared__ unsigned tot[256];
  int tid = threadIdx.x; int s = blockIdx.x;
  unsigned* g = hist + s*16384;
  unsigned sum = 0;
  for (int q = 0; q < 64; ++q) sum += g[tid*64 + q];
  tot[tid] = sum;
  __syncthreads();
  if (tid == 0){
    unsigned run = 0;
    for (int t = 0; t < 256; ++t){ unsigned tmp = tot[t]; tot[t] = run; run += tmp; }
  }
  __syncthreads();
  unsigned run = tot[tid];
  for (int q = 0; q < 64; ++q){ unsigned tmp = g[tid*64+q]; g[tid*64+q] = run; run += tmp; }
}

#define EPT 16
__global__ __launch_bounds__(128) void k_scatter(const unsigned* __restrict__ srcK,
    const unsigned* __restrict__ srcV, unsigned* __restrict__ dstK, unsigned* __restrict__ dstV,
    const unsigned* __restrict__ off, int shift){
  __shared__ unsigned short cnt[256*128];
  int tid = threadIdx.x;
  unsigned* cz = (unsigned*)cnt;
  for (int idx = tid; idx < 256*128/2; idx += 128) cz[idx] = 0u;
  __syncthreads();
  int s = blockIdx.x / TPS, tile = blockIdx.x % TPS;
  const unsigned* ks = srcK + (size_t)s*NPOS + (size_t)tile*TILE;
  const unsigned* vs = srcV + (size_t)s*NPOS + (size_t)tile*TILE;
  unsigned k8[EPT], v8[EPT];
  #pragma unroll
  for (int r = 0; r < EPT; ++r){
    k8[r] = ks[tid*EPT + r];
    v8[r] = vs[tid*EPT + r];
    unsigned d = (k8[r] >> shift) & 255u;
    cnt[d*128 + tid]++;
  }
  __syncthreads();
  for (int dd = 0; dd < 2; ++dd){
    int d = tid + dd*128;
    unsigned run = 0;
    for (int t = 0; t < 128; ++t){ unsigned tmp = cnt[d*128 + t]; cnt[d*128 + t] = (unsigned short)run; run += tmp; }
  }
  __syncthreads();
  const unsigned* ob = off + s*16384;
  #pragma unroll
  for (int r = 0; r < EPT; ++r){
    unsigned d = (k8[r] >> shift) & 255u;
    unsigned rk = cnt[d*128 + tid];
    cnt[d*128 + tid] = (unsigned short)(rk + 1u);
    unsigned pos = ob[d*TPS + tile] + rk;
    dstK[(size_t)s*NPOS + pos] = k8[r];
    dstV[(size_t)s*NPOS + pos] = v8[r];
  }
}

// ---------------- gather: fill XA[224] ch0..68 + zeros, Xcat[272] ch4..72,201..269,270..271 ----
__global__ __launch_bounds__(256) void k_gath(const float* __restrict__ inp,
    const unsigned* __restrict__ P1, const unsigned* __restrict__ P0,
    short* __restrict__ XA, short* __restrict__ Xcat, int b){
  int t = blockIdx.x*256 + threadIdx.x;   // NPOS*128
  int i = t >> 7, c = t & 127;
  const float* r1 = inp + ((size_t)b*NPOS + P1[i])*NF;
  if (c < 69){
    short v = f2bf(r1[c]);
    XA[(size_t)i*224 + c] = v;
    Xcat[(size_t)i*272 + 4 + c] = v;
    const float* r0 = inp + ((size_t)b*NPOS + P0[i])*NF;
    Xcat[(size_t)i*272 + 201 + c] = f2bf(r0[c]);
  } else if (c == 69){
    Xcat[(size_t)i*272 + 270] = 0;
    Xcat[(size_t)i*272 + 271] = 0;
  }
  int c2 = c + 128;
  if (c2 >= 197 && c2 < 224) XA[(size_t)i*224 + c2] = 0;
}

// ---------------- weight prep: f32 [3][cin][128] -> bf16 B^T [128][3*CPAD] ----------------
__global__ void k_prepw3(const float* __restrict__ w, short* __restrict__ out, int cin, int CPAD){
  int t = blockIdx.x*256 + threadIdx.x;
  int total = 128*3*CPAD;
  if (t >= total) return;
  int nn = t / (3*CPAD), rest = t % (3*CPAD);
  int tap = rest / CPAD, c = rest % CPAD;
  out[t] = (c < cin) ? f2bf(w[((size_t)tap*cin + c)*128 + nn]) : (short)0;
}
__global__ void k_prepwm(const float* __restrict__ w, short* __restrict__ out){
  int t = blockIdx.x*256 + threadIdx.x;   // 128*1088
  if (t >= 128*1088) return;
  int nn = t / 1088, rest = t % 1088;
  int tap = rest / 272, c = rest % 272;
  out[t] = (c < 270) ? f2bf(w[((size_t)tap*270 + c)*128 + nn]) : (short)0;
}

// ---------------- MFMA conv3 (SAME, stride1): GEMM with 3-tap shifted A ----------------
// src: bf16 rows stride sstride, channels [0,cin) valid (rest zero-padded in LDS)
// wB:  bf16 [128][3*CPAD];  dst: bf16, stride dstride (base pre-offset to channel slot)
template<int CPAD>
__global__ __launch_bounds__(256) void k_convm(
    const short* __restrict__ src, int sstride, int cin,
    const short* __restrict__ wB, const float* __restrict__ bias,
    short* __restrict__ dst, int dstride, int n)
{
  constexpr int KT = CPAD/32;
  constexpr int NS = 3*KT;
  constexpr int ASTR = CPAD + 8;       // +8 shorts: 2-way-free bank spread
  __shared__ short A_s[66*ASTR];
  __shared__ short B_s[2][128*40];
  int tid = threadIdx.x;
  int i0 = blockIdx.x*64;
  // stage A (once): rows i0-1 .. i0+64
  constexpr int AG = CPAD/8;
  for (int idx = tid; idx < 66*AG; idx += 256){
    int r = idx / AG, g = idx - r*AG;
    int pos = i0 - 1 + r;
    short8 v = {0,0,0,0,0,0,0,0};
    if (pos >= 0 && pos < n){
      if ((g+1)*8 <= cin){
        v = *(const short8*)(src + (size_t)pos*sstride + g*8);
      } else if (g*8 < cin){
        const short* p = src + (size_t)pos*sstride;
        #pragma unroll
        for (int j = 0; j < 8; ++j) if (g*8+j < cin) v[j] = p[g*8+j];
      }
    }
    *(short8*)((char*)A_s + r*ASTR*2 + g*16) = v;
  }
  auto stageB = [&](int s, int buf){
    #pragma unroll
    for (int idx = tid; idx < 512; idx += 256){
      int nn = idx >> 2, q = idx & 3;
      short8 v = *(const short8*)(wB + (size_t)nn*(3*CPAD) + s*32 + q*8);
      *(short8*)((char*)B_s[buf] + nn*80 + q*16) = v;
    }
  };
  stageB(0, 0);
  __syncthreads();
  int wv = tid >> 6, lane = tid & 63;
  int lm = lane & 15, lk = lane >> 4;
  f32x4 acc[4][2] = {};
  for (int s = 0; s < NS; ++s){
    int buf = s & 1;
    if (s+1 < NS) stageB(s+1, buf^1);
    int tp = s / KT, ksub = s - tp*KT;
    bf16x8 a[4], b[2];
    #pragma unroll
    for (int mi = 0; mi < 4; ++mi){
      int r = mi*16 + lm + tp;
      a[mi] = as_bf16x8(*(short8*)((char*)A_s + r*ASTR*2 + (ksub*32 + lk*8)*2));
    }
    #pragma unroll
    for (int ni = 0; ni < 2; ++ni){
      int nn = wv*32 + ni*16 + lm;
      b[ni] = as_bf16x8(*(short8*)((char*)B_s[buf] + nn*80 + lk*16));
    }
    #pragma unroll
    for (int mi = 0; mi < 4; ++mi)
      #pragma unroll
      for (int ni = 0; ni < 2; ++ni)
        acc[mi][ni] = __builtin_amdgcn_mfma_f32_16x16x32_bf16(a[mi], b[ni], acc[mi][ni], 0, 0, 0);
    __syncthreads();
  }
  #pragma unroll
  for (int mi = 0; mi < 4; ++mi)
    #pragma unroll
    for (int ni = 0; ni < 2; ++ni){
      int nn = wv*32 + ni*16 + lm;
      float bs = bias[nn];
      #pragma unroll
      for (int r = 0; r < 4; ++r){
        int pos = i0 + mi*16 + lk*4 + r;
        dst[(size_t)pos*dstride + nn] = f2bf(fmaxf(acc[mi][ni][r] + bs, 0.f));
      }
    }
}

// ---------------- MFMA merge: pure GEMM (32768 x 1088) x (1088 x 128) ----------------
__global__ __launch_bounds__(256) void k_mergem(const short* __restrict__ Xf,
    const short* __restrict__ wB, const float* __restrict__ bias, short* __restrict__ dst)
{
  __shared__ short A_s[2][64*40];
  __shared__ short B_s[2][128*40];
  int tid = threadIdx.x;
  int j0 = blockIdx.x*64;
  auto stageA = [&](int s, int buf){
    int r = tid >> 2, q = tid & 3;     // 256 = 64 rows x 4 chunks
    short8 v = *(const short8*)(Xf + (size_t)(j0 + r)*1088 + s*32 + q*8);
    *(short8*)((char*)A_s[buf] + r*80 + q*16) = v;
  };
  auto stageB = [&](int s, int buf){
    #pragma unroll
    for (int idx = tid; idx < 512; idx += 256){
      int nn = idx >> 2, q = idx & 3;
      short8 v = *(const short8*)(wB + (size_t)nn*1088 + s*32 + q*8);
      *(short8*)((char*)B_s[buf] + nn*80 + q*16) = v;
    }
  };
  stageA(0, 0); stageB(0, 0);
  __syncthreads();
  int wv = tid >> 6, lane = tid & 63;
  int lm = lane & 15, lk = lane >> 4;
  f32x4 acc[4][2] = {};
  for (int s = 0; s < 34; ++s){
    int buf = s & 1;
    if (s+1 < 34){ stageA(s+1, buf^1); stageB(s+1, buf^1); }
    bf16x8 a[4], b[2];
    #pragma unroll
    for (int mi = 0; mi < 4; ++mi){
      int r = mi*16 + lm;
      a[mi] = as_bf16x8(*(short8*)((char*)A_s[buf] + r*80 + lk*16));
    }
    #pragma unroll
    for (int ni = 0; ni < 2; ++ni){
      int nn = wv*32 + ni*16 + lm;
      b[ni] = as_bf16x8(*(short8*)((char*)B_s[buf] + nn*80 + lk*16));
    }
    #pragma unroll
    for (int mi = 0; mi < 4; ++mi)
      #pragma unroll
      for (int ni = 0; ni < 2; ++ni)
        acc[mi][ni] = __builtin_amdgcn_mfma_f32_16x16x32_bf16(a[mi], b[ni], acc[mi][ni], 0, 0, 0);
    __syncthreads();
  }
  #pragma unroll
  for (int mi = 0; mi < 4; ++mi)
    #pragma unroll
    for (int ni = 0; ni < 2; ++ni){
      int nn = wv*32 + ni*16 + lm;
      float bs = bias[nn];
      #pragma unroll
      for (int r = 0; r < 4; ++r){
        int pos = j0 + mi*16 + lk*4 + r;
        dst[(size_t)pos*128 + nn] = f2bf(fmaxf(acc[mi][ni][r] + bs, 0.f));
      }
    }
}

// ---------------- flags head: sigmoid(X3 @ Wf + bf), f32 math on bf16 inputs ----------------
__global__ __launch_bounds__(256) void k_flags2(const short* __restrict__ XA,
    short* __restrict__ Xcat, const float* __restrict__ Wf, const float* __restrict__ bf,
    float* __restrict__ F){
  size_t i = (size_t)blockIdx.x*256 + threadIdx.x;
  float a0 = bf[0], a1 = bf[1], a2 = bf[2], a3 = bf[3];
  const short* x0 = XA + i*224;
  for (int c = 0; c < 69; ++c){
    float x = bf2f(x0[c]); const float* w = Wf + c*4;
    a0 = fmaf(x,w[0],a0); a1 = fmaf(x,w[1],a1); a2 = fmaf(x,w[2],a2); a3 = fmaf(x,w[3],a3);
  }
  const short* bc = Xcat + i*272 + 73;
  for (int c = 0; c < 128; ++c){
    float x = bf2f(bc[c]); const float* w = Wf + (69 + c)*4;
    a0 = fmaf(x,w[0],a0); a1 = fmaf(x,w[1],a1); a2 = fmaf(x,w[2],a2); a3 = fmaf(x,w[3],a3);
  }
  const short* g = Xcat + i*272 + 201;
  for (int c = 0; c < 69; ++c){
    float x = bf2f(g[c]); const float* w = Wf + (197 + c)*4;
    a0 = fmaf(x,w[0],a0); a1 = fmaf(x,w[1],a1); a2 = fmaf(x,w[2],a2); a3 = fmaf(x,w[3],a3);
  }
  float f0 = 1.f/(1.f+expf(-a0)), f1 = 1.f/(1.f+expf(-a1));
  float f2 = 1.f/(1.f+expf(-a2)), f3 = 1.f/(1.f+expf(-a3));
  float* f = F + i*4;
  f[0]=f0; f[1]=f1; f[2]=f2; f[3]=f3;
  short* xc = Xcat + i*272;
  xc[0]=f2bf(f0); xc[1]=f2bf(f1); xc[2]=f2bf(f2); xc[3]=f2bf(f3);
}

// ---------------- output head: softmax(S@Ws+bs) + flag diff, f32 out ----------------
__global__ __launch_bounds__(256) void k_out(const short* __restrict__ S,
    const float* __restrict__ F, const float* __restrict__ Ws, const float* __restrict__ bs,
    float* __restrict__ out, int b){
  size_t j = (size_t)blockIdx.x*256 + threadIdx.x;
  float l[16];
  #pragma unroll
  for (int t = 0; t < 16; ++t) l[t] = bs[t];
  const short* s = S + j*128;
  for (int c = 0; c < 128; ++c){
    float x = bf2f(s[c]); const float* w = Ws + c*16;
    #pragma unroll
    for (int t = 0; t < 16; ++t) l[t] = fmaf(x, w[t], l[t]);
  }
  float m = l[0];
  #pragma unroll
  for (int t = 1; t < 16; ++t) m = fmaxf(m, l[t]);
  float sum = 0.f;
  #pragma unroll
  for (int t = 0; t < 16; ++t){ l[t] = expf(l[t]-m); sum += l[t]; }
  float inv = 1.f/sum;
  float* o = out + ((size_t)b*NMRG + j)*20;
  #pragma unroll
  for (int k = 0; k < 4; ++k){
    size_t r = (size_t)(4*j + k)*4;
    o[k] = F[r] - F[r+1];
  }
  #pragma unroll
  for (int t = 0; t < 16; ++t) o[4+t] = l[t]*inv;
}

extern "C" void kernel_launch(void* const* d_in, const int* in_sizes, int n_in,
                              void* d_out, int out_size, void* d_ws, size_t ws_size,
                              hipStream_t stream){
  const float* inp     = (const float*)d_in[0];
  const float* w_pre0  = (const float*)d_in[1];
  const float* b_pre0  = (const float*)d_in[2];
  const float* w_pre1  = (const float*)d_in[3];
  const float* b_pre1  = (const float*)d_in[4];
  const float* w_flags = (const float*)d_in[5];
  const float* b_flags = (const float*)d_in[6];
  const float* w_merge = (const float*)d_in[7];
  const float* b_merge = (const float*)d_in[8];
  const float* w_post[4] = {(const float*)d_in[9], (const float*)d_in[11],
                            (const float*)d_in[13], (const float*)d_in[15]};
  const float* b_post[4] = {(const float*)d_in[10], (const float*)d_in[12],
                            (const float*)d_in[14], (const float*)d_in[16]};
  const float* w_sym   = (const float*)d_in[17];
  const float* b_sym   = (const float*)d_in[18];
  float* outp = (float*)d_out;

  char* p = (char*)d_ws;
  unsigned* kA = (unsigned*)p; p += (size_t)NSORT*NPOS*4;
  unsigned* vA = (unsigned*)p; p += (size_t)NSORT*NPOS*4;
  unsigned* kB = (unsigned*)p; p += (size_t)NSORT*NPOS*4;
  unsigned* vB = (unsigned*)p; p += (size_t)NSORT*NPOS*4;
  unsigned* hist = (unsigned*)p; p += (size_t)NSORT*16384*4;
  short* XA   = (short*)p; p += (size_t)NPOS*224*2;
  short* Xcat = (short*)p; p += (size_t)NPOS*272*2;
  float* Fbuf = (float*)p; p += (size_t)NPOS*4*4;
  short* M0   = (short*)p; p += (size_t)NMRG*128*2;
  short* M1   = (short*)p; p += (size_t)NMRG*128*2;
  short* wbp0 = (short*)p; p += (size_t)128*288*2;
  short* wbp1 = (short*)p; p += (size_t)128*672*2;
  short* wbq0 = (short*)p; p += (size_t)128*384*2;
  short* wbq1 = (short*)p; p += (size_t)128*384*2;
  short* wbq2 = (short*)p; p += (size_t)128*384*2;
  short* wbq3 = (short*)p; p += (size_t)128*384*2;
  short* wbm  = (short*)p; p += (size_t)128*1088*2;
  if ((size_t)(p - (char*)d_ws) > ws_size) return;
  short* wbq[4] = {wbq0, wbq1, wbq2, wbq3};

  // weight prep (cheap, once per call)
  k_prepw3<<<(128*288 +255)/256, 256, 0, stream>>>(w_pre0, wbp0, 69, 96);
  k_prepw3<<<(128*672 +255)/256, 256, 0, stream>>>(w_pre1, wbp1, 197, 224);
  for (int i = 0; i < 4; ++i)
    k_prepw3<<<(128*384 +255)/256, 256, 0, stream>>>(w_post[i], wbq[i], 128, 128);
  k_prepwm<<<(128*1088+255)/256, 256, 0, stream>>>(w_merge, wbm);

  // sorts
  k_make_keys<<<NSORT*NPOS/256, 256, 0, stream>>>(inp, kA, vA);
  unsigned *sk = kA, *sv = vA, *dk = kB, *dv = vB;
  for (int pass = 0; pass < 4; ++pass){
    int shift = pass*8;
    k_hist<<<NSORT*TPS, 256, 0, stream>>>(sk, hist, shift);
    k_scan<<<NSORT, 256, 0, stream>>>(hist);
    k_scatter<<<NSORT*TPS, 128, 0, stream>>>(sk, sv, dk, dv, hist, shift);
    unsigned* t;
    t = sk; sk = dk; dk = t;
    t = sv; sv = dv; dv = t;
  }
  for (int b = 0; b < 2; ++b){
    const unsigned* P0 = sv + (size_t)(b*2+0)*NPOS;  // argsort of ch 3
    const unsigned* P1 = sv + (size_t)(b*2+1)*NPOS;  // argsort of ch 4
    k_gath<<<NPOS*128/256, 256, 0, stream>>>(inp, P1, P0, XA, Xcat, b);
    k_convm<96> <<<NPOS/64, 256, 0, stream>>>(XA, 224, 69,  wbp0, b_pre0, XA + 69,   224, NPOS);
    k_convm<224><<<NPOS/64, 256, 0, stream>>>(XA, 224, 224, wbp1, b_pre1, Xcat + 73, 272, NPOS);
    k_flags2<<<NPOS/256, 256, 0, stream>>>(XA, Xcat, w_flags, b_flags, Fbuf);
    k_mergem<<<NMRG/64, 256, 0, stream>>>(Xcat, wbm, b_merge, M0);
    k_convm<128><<<NMRG/64, 256, 0, stream>>>(M0, 128, 128, wbq[0], b_post[0], M1, 128, NMRG);
    k_convm<128><<<NMRG/64, 256, 0, stream>>>(M1, 128, 128, wbq[1], b_post[1], M0, 128, NMRG);
    k_convm<128><<<NMRG/64, 256, 0, stream>>>(M0, 128, 128, wbq[2], b_post[2], M1, 128, NMRG);
    k_convm<128><<<NMRG/64, 256, 0, stream>>>(M1, 128, 128, wbq[3], b_post[3], M0, 128, NMRG);
    k_out<<<NMRG/256, 256, 0, stream>>>(M0, Fbuf, w_sym, b_sym, outp, b);
  }
}